// Round 20
// baseline (1427.183 us; speedup 1.0000x reference)
//
#include <hip/hip_runtime.h>

#define B_ 8
#define N_ 4096
#define K_ 1024
#define NN_ 16
#define C1_ 128
#define C2_ 128
#define CIN_ 67
#define NROWS (B_*K_*NN_)   // 131072
#define NBLK  (NROWS/64)    // 2048 stats1 tiles
#define NBLK2 (NROWS/32)    // 4096 gemm2 tiles
#define BN_N 131072.0f

typedef unsigned short u16;

__device__ u16   g_knn[NROWS];
// BN accumulators, 8-way slot-spread (r19: cut atomic serialization ~150 us).
__device__ float g_statsA[8*256];               // BN1 sum/sumsq per slot
__device__ float g_statsB[8*256];               // BN2 sum/sumsq per slot
__device__ float g_m2[B_*K_*C2_];
__device__ float g_W1T[68*128];                 // W1^T [q][o], row 67 zeroed
__device__ float g_W2T[128*128];                // W2^T [q][o]
__device__ __align__(16) float g_h1[(size_t)NROWS*128];   // pre-BN1 h1 (64 MB)

// --------------------------------------------------- DPP wave reduction ----
// Value-only max reduce-to-lane-63 (12 inst). Index resolved via ballot +
// ffs + readlane — exact for fps (blocked ascending per-lane index ranges).
template<int CTRL>
static __device__ __forceinline__ void dpp_maxv_step(float& v) {
    int vi = __float_as_int(v);
    int ov = __builtin_amdgcn_update_dpp(vi, vi, CTRL, 0xf, 0xf, false);
    v = fmaxf(v, __int_as_float(ov));
}
static __device__ __forceinline__ void wave_reduce_maxval(float& v) {
    dpp_maxv_step<0x111>(v);
    dpp_maxv_step<0x112>(v);
    dpp_maxv_step<0x114>(v);
    dpp_maxv_step<0x118>(v);
    dpp_maxv_step<0x142>(v);
    dpp_maxv_step<0x143>(v);   // lane 63 holds max
}
// kNN keeps the lexicographic pair reduce (its indices are interleaved).
template<int CTRL>
static __device__ __forceinline__ void dpp_min_step(float& v, int& ib) {
    int vi = __float_as_int(v);
    int ov = __builtin_amdgcn_update_dpp(vi, vi, CTRL, 0xf, 0xf, false);
    int oi = __builtin_amdgcn_update_dpp(ib, ib, CTRL, 0xf, 0xf, false);
    float of = __int_as_float(ov);
    if (of < v || (of == v && oi < ib)) { v = of; ib = oi; }
}
static __device__ __forceinline__ void wave_reduce_min(float& v, int& ib) {
    dpp_min_step<0x111>(v, ib);
    dpp_min_step<0x112>(v, ib);
    dpp_min_step<0x114>(v, ib);
    dpp_min_step<0x118>(v, ib);
    dpp_min_step<0x142>(v, ib);
    dpp_min_step<0x143>(v, ib);
}

// ------------------------------------- weight transpose + stats zeroing ----
__global__ void transpose_w_kernel(const float* __restrict__ W1,
                                   const float* __restrict__ W2) {
    int t = blockIdx.x * 256 + threadIdx.x;
    if (t < 8*256) { g_statsA[t] = 0.f; g_statsB[t] = 0.f; }
    if (t < 68*128) {
        int q = t >> 7, o = t & 127;
        g_W1T[t] = (q < CIN_) ? W1[o*CIN_ + q] : 0.f;
    }
    if (t < 128*128) {
        int q = t >> 7, o = t & 127;
        g_W2T[t] = W2[o*C1_ + q];
    }
}

// ---------------------------------------------------------------- FPS ------
// v10 = r18/r19's 1-barrier ballot structure at 1024 threads (4 waves/SIMD).
// r19 counters: VALUBusy 1.74% over 256 CUs = ~56% per active CU -> ~800
// cyc/step of issue on 1 wave/SIMD with all latencies exposed. 4 waves/SIMD
// interleave issue with DPP/LDS latency; still ONE barrier/step.
// Selection exact: lane l of wave w owns points (w*64+l)*4 + j (blocked,
// ascending), so per-lane first-max + lowest-tied-lane ballot + strict->
// cross-wave merge over ascending waves == jnp.argmax (10 passing rounds).
__global__ __launch_bounds__(1024) void fps_kernel(const float* __restrict__ xyz,
                                                   float* __restrict__ out_xyz) {
    __shared__ float sx[N_*3];                         // 48 KB xyz copy
    __shared__ float sout[K_*3];                       // 12 KB centroids
    __shared__ __align__(16) float wv[2][16];
    __shared__ __align__(16) int   wi[2][16];
    const int b = blockIdx.x, t = threadIdx.x;
    const int l = t & 63, w = t >> 6;
    const float* xb = xyz + b * (N_ * 3);
    for (int e = t; e < N_*3; e += 1024) sx[e] = xb[e];
    __syncthreads();
    float x0[4], y0[4], z0[4], dist[4];
    #pragma unroll
    for (int j = 0; j < 4; ++j) {
        int p = t * 4 + j;
        x0[j] = sx[p*3+0]; y0[j] = sx[p*3+1]; z0[j] = sx[p*3+2];
        dist[j] = 1e10f;
    }
    int far = 0;
    for (int s = 0; s < K_; ++s) {
        const float cx = sx[far*3+0], cy = sx[far*3+1], cz = sx[far*3+2];
        if (t == 0) {
            sout[s*3+0] = cx; sout[s*3+1] = cy; sout[s*3+2] = cz;
        }
        float v = -1.f; int ib = 0;
        {
            #pragma clang fp contract(fast)
            #pragma unroll
            for (int j = 0; j < 4; ++j) {
                float dx = x0[j]-cx, dy = y0[j]-cy, dz = z0[j]-cz;
                float dd = dx*dx + dy*dy + dz*dz;
                dd = fminf(dist[j], dd);
                dist[j] = dd;
                if (dd > v) { v = dd; ib = t*4 + j; }   // ascending j: first max
            }
        }
        float vr = v;
        wave_reduce_maxval(vr);
        const float m = __int_as_float(__builtin_amdgcn_readlane(__float_as_int(vr), 63));
        unsigned long long mk = __ballot(v == m);
        const int ln  = __ffsll((unsigned long long)mk) - 1;   // lowest tied lane
        const int wib = __builtin_amdgcn_readlane(ib, ln);
        const int pb = s & 1;
        if (l == 0) { wv[pb][w] = m; wi[pb][w] = wib; }
        __syncthreads();                   // only barrier per step
        const float4* pv = (const float4*)&wv[pb][0];
        const int4*   pi = (const int4*)&wi[pb][0];
        float4 v0 = pv[0], v1 = pv[1], v2 = pv[2], v3 = pv[3];
        int4   i0 = pi[0], i1 = pi[1], i2 = pi[2], i3 = pi[3];
        float bv = v0.x; int bi = i0.x;            // waves ascend idx; strict >
        if (v0.y > bv) { bv = v0.y; bi = i0.y; }
        if (v0.z > bv) { bv = v0.z; bi = i0.z; }
        if (v0.w > bv) { bv = v0.w; bi = i0.w; }
        if (v1.x > bv) { bv = v1.x; bi = i1.x; }
        if (v1.y > bv) { bv = v1.y; bi = i1.y; }
        if (v1.z > bv) { bv = v1.z; bi = i1.z; }
        if (v1.w > bv) { bv = v1.w; bi = i1.w; }
        if (v2.x > bv) { bv = v2.x; bi = i2.x; }
        if (v2.y > bv) { bv = v2.y; bi = i2.y; }
        if (v2.z > bv) { bv = v2.z; bi = i2.z; }
        if (v2.w > bv) { bv = v2.w; bi = i2.w; }
        if (v3.x > bv) { bv = v3.x; bi = i3.x; }
        if (v3.y > bv) { bv = v3.y; bi = i3.y; }
        if (v3.z > bv) { bv = v3.z; bi = i3.z; }
        if (v3.w > bv) { bv = v3.w; bi = i3.w; }
        far = bi & 4095;
    }
    __syncthreads();                       // sout complete
    for (int e = t; e < K_*3; e += 1024) out_xyz[b*K_*3 + e] = sout[e];
}

// ---------------------------------------------------------------- kNN ------
__global__ __launch_bounds__(256) void knn_kernel(const float* __restrict__ xyz,
                                                  const float* __restrict__ newxyz) {
    __shared__ float px[N_], py[N_], pz[N_];
    const int b = blockIdx.y, t = threadIdx.x;
    const int l = t & 63, w = t >> 6;
    const int k = blockIdx.x * 4 + w;
    const int m = b*K_ + k;
    const float* xb = xyz + b * (N_ * 3);
    for (int p = t; p < N_; p += 256) {
        px[p] = xb[p*3+0]; py[p] = xb[p*3+1]; pz[p] = xb[p*3+2];
    }
    __syncthreads();
    const float cx = newxyz[m*3+0];
    const float cy = newxyz[m*3+1];
    const float cz = newxyz[m*3+2];
    float d[64];
    {
        #pragma clang fp contract(off)
        float sn = cx*cx; sn = sn + cy*cy; sn = sn + cz*cz;
        #pragma unroll
        for (int j = 0; j < 64; ++j) {
            int p = j*64 + l;
            float X = px[p], Y = py[p], Z = pz[p];
            float sp = X*X; sp = sp + Y*Y; sp = sp + Z*Z;
            float dt = cx*X; dt = dt + cy*Y; dt = dt + cz*Z;
            float t1 = sn + sp;
            d[j] = t1 - 2.0f*dt;
        }
    }
    float prevd = -1e38f; int previ = -1;
    for (int r = 0; r < NN_; ++r) {
        float bv = 1e38f; int bi = 0x7fffffff;
        #pragma unroll
        for (int j = 0; j < 64; ++j) {
            int p = j*64 + l;
            bool gt = (d[j] > prevd) || (d[j] == prevd && p > previ);
            bool lt = (d[j] < bv)   || (d[j] == bv   && p < bi);
            if (gt && lt) { bv = d[j]; bi = p; }
        }
        wave_reduce_min(bv, bi);
        previ = __builtin_amdgcn_readlane(bi, 63);
        prevd = __int_as_float(__builtin_amdgcn_readlane(__float_as_int(bv), 63));
        if (l == 0) g_knn[m*NN_ + r] = (u16)(previ & 4095);
    }
}

// ------------------------------------------------- GEMM1 + stats + h1 ------
__global__ __launch_bounds__(256) void stats1_kernel(
        const float* __restrict__ xyz, const float* __restrict__ points,
        const float* __restrict__ newxyz, const float* __restrict__ b1) {
    __shared__ union {
        float Xs[64][68];
        struct { float ps[16][128], pq[16][128]; } c;
    } u;
    __shared__ float cen[4][3];
    __shared__ int rowp[64];
    const int t = threadIdx.x;
    const int blk = blockIdx.x;
    const int b = blk >> 8;
    const int g0 = blk * 64;
    if (t < 64)  rowp[t] = ((int)g_knn[g0 + t]) & 4095;
    if (t < 12)  cen[t/3][t%3] = newxyz[(blk*4 + t/3)*3 + (t%3)];
    __syncthreads();
    for (int e = t; e < 64*68; e += 256) {
        int r = e / 68, c = e % 68;
        int p = rowp[r];
        float v = 0.f;
        if (c < 3)         v = xyz[(b*N_ + p)*3 + c] - cen[r >> 4][c];
        else if (c < CIN_) v = points[(b*N_ + p)*64 + (c - 3)];
        u.Xs[r][c] = v;
    }
    __syncthreads();
    const int rg = t >> 4, cg = t & 15;
    const int r0 = rg * 4;
    float acc[4][8];
    #pragma unroll
    for (int j = 0; j < 4; ++j)
        #pragma unroll
        for (int i = 0; i < 8; ++i) acc[j][i] = 0.f;
    for (int q4 = 0; q4 < 17; ++q4) {
        float4 xv[4];
        #pragma unroll
        for (int j = 0; j < 4; ++j) xv[j] = *(const float4*)&u.Xs[r0 + j][q4*4];
        #pragma unroll
        for (int i = 0; i < 8; ++i) {
            int o = cg + 16*i;
            float w0 = g_W1T[(q4*4+0)*128 + o];
            float w1 = g_W1T[(q4*4+1)*128 + o];
            float w2 = g_W1T[(q4*4+2)*128 + o];
            float w3 = g_W1T[(q4*4+3)*128 + o];
            #pragma unroll
            for (int j = 0; j < 4; ++j) {
                float a = acc[j][i];
                a = a + xv[j].x*w0; a = a + xv[j].y*w1;
                a = a + xv[j].z*w2; a = a + xv[j].w*w3;
                acc[j][i] = a;
            }
        }
    }
    __syncthreads();   // Xs reads done -> union reusable
    #pragma unroll
    for (int i = 0; i < 8; ++i) {
        int o = cg + 16*i;
        float bias = b1[o];
        float s = 0.f, sq = 0.f;
        #pragma unroll
        for (int j = 0; j < 4; ++j) {
            float v = acc[j][i] + bias;
            g_h1[(size_t)(g0 + r0 + j)*128 + o] = v;
            s += v; sq += v*v;
        }
        u.c.ps[rg][o] = s; u.c.pq[rg][o] = sq;
    }
    __syncthreads();
    if (t < 128) {
        float ts = 0.f, tq = 0.f;
        #pragma unroll
        for (int g = 0; g < 16; ++g) { ts += u.c.ps[g][t]; tq += u.c.pq[g][t]; }
        const int slot = (blk & 7) * 256;
        atomicAdd(&g_statsA[slot + t], ts);
        atomicAdd(&g_statsA[slot + 128 + t], tq);
    }
}

// ------------------------------------------------ BN1+ReLU + GEMM2 ---------
__global__ __launch_bounds__(256) void gemm2_kernel(
        const float* __restrict__ b2, const float* __restrict__ g1,
        const float* __restrict__ be1) {
    __shared__ float mn1[128], sc1[128], bb1[128];
    __shared__ union {
        float h1s[32][132];
        struct { float ps[16][128], pq[16][128], pm[16][128]; } c;
    } u;
    const int t = threadIdx.x;
    const int blk = blockIdx.x;
    const int g0 = blk * 32;
    if (t < 128) {
        float sum = 0.f, sq = 0.f;
        #pragma unroll
        for (int s = 0; s < 8; ++s) {
            sum += g_statsA[s*256 + t];
            sq  += g_statsA[s*256 + 128 + t];
        }
        float mean = sum * (1.f / BN_N);
        float var  = sq * (1.f / BN_N) - mean*mean;
        mn1[t] = mean; sc1[t] = (1.f / sqrtf(var + 1e-5f)) * g1[t];
        bb1[t] = be1[t];
    }
    __syncthreads();
    for (int e = t*4; e < 32*128; e += 1024) {
        float4 hv = *(const float4*)&g_h1[(size_t)g0*128 + e];
        int r = e >> 7, c = e & 127;
        u.h1s[r][c+0] = fmaxf((hv.x - mn1[c+0])*sc1[c+0] + bb1[c+0], 0.f);
        u.h1s[r][c+1] = fmaxf((hv.y - mn1[c+1])*sc1[c+1] + bb1[c+1], 0.f);
        u.h1s[r][c+2] = fmaxf((hv.z - mn1[c+2])*sc1[c+2] + bb1[c+2], 0.f);
        u.h1s[r][c+3] = fmaxf((hv.w - mn1[c+3])*sc1[c+3] + bb1[c+3], 0.f);
    }
    __syncthreads();
    const int rg = t >> 4, cg = t & 15;
    const int r0 = rg * 2;
    float acc2[2][8];
    #pragma unroll
    for (int j = 0; j < 2; ++j)
        #pragma unroll
        for (int i = 0; i < 8; ++i) acc2[j][i] = 0.f;
    for (int q4 = 0; q4 < 32; ++q4) {
        float4 xv0 = *(const float4*)&u.h1s[r0][q4*4];
        float4 xv1 = *(const float4*)&u.h1s[r0+1][q4*4];
        #pragma unroll
        for (int i = 0; i < 8; ++i) {
            int o = cg + 16*i;
            float w0 = g_W2T[(q4*4+0)*128 + o];
            float w1 = g_W2T[(q4*4+1)*128 + o];
            float w2 = g_W2T[(q4*4+2)*128 + o];
            float w3 = g_W2T[(q4*4+3)*128 + o];
            float a0 = acc2[0][i];
            a0 = a0 + xv0.x*w0; a0 = a0 + xv0.y*w1;
            a0 = a0 + xv0.z*w2; a0 = a0 + xv0.w*w3;
            acc2[0][i] = a0;
            float a1 = acc2[1][i];
            a1 = a1 + xv1.x*w0; a1 = a1 + xv1.y*w1;
            a1 = a1 + xv1.z*w2; a1 = a1 + xv1.w*w3;
            acc2[1][i] = a1;
        }
    }
    __syncthreads();   // h1s reads done -> union reusable
    #pragma unroll
    for (int i = 0; i < 8; ++i) {
        int o = cg + 16*i;
        float bias = b2[o];
        float s = 0.f, sq = 0.f, mx = -1e38f;
        #pragma unroll
        for (int j = 0; j < 2; ++j) {
            float v = acc2[j][i] + bias;
            s += v; sq += v*v; mx = fmaxf(mx, v);
        }
        u.c.ps[rg][o] = s; u.c.pq[rg][o] = sq; u.c.pm[rg][o] = mx;
    }
    __syncthreads();
    if (t < 128) {
        float ts = 0.f, tq = 0.f;
        #pragma unroll
        for (int g = 0; g < 16; ++g) { ts += u.c.ps[g][t]; tq += u.c.pq[g][t]; }
        const int slot = (blk & 7) * 256;
        atomicAdd(&g_statsB[slot + t], ts);
        atomicAdd(&g_statsB[slot + 128 + t], tq);
    }
    {
        const int o = t & 127, gg = t >> 7;
        float mx = u.c.pm[gg*8 + 0][o];
        #pragma unroll
        for (int g = 1; g < 8; ++g) mx = fmaxf(mx, u.c.pm[gg*8 + g][o]);
        g_m2[(blk*2 + gg)*128 + o] = mx;
    }
}

// ------------------------------------------------------------- finalize ----
__global__ __launch_bounds__(256) void final_kernel(
        const float* __restrict__ g2, const float* __restrict__ be2,
        float* __restrict__ outp) {
    __shared__ float mn[128], sc[128], bb[128];
    const int t = threadIdx.x;
    if (t < 128) {
        float sum = 0.f, sq = 0.f;
        #pragma unroll
        for (int s = 0; s < 8; ++s) {
            sum += g_statsB[s*256 + t];
            sq  += g_statsB[s*256 + 128 + t];
        }
        float mean = sum * (1.f / BN_N);
        float var  = sq * (1.f / BN_N) - mean*mean;
        float inv  = 1.f / sqrtf(var + 1e-5f);
        mn[t] = mean; sc[t] = inv * g2[t]; bb[t] = be2[t];
    }
    __syncthreads();
    const int m = blockIdx.x*2 + (t >> 7);
    const int c = t & 127;
    float v = (g_m2[m*128 + c] - mn[c]) * sc[c] + bb[c];
    v = fmaxf(v, 0.f);
    outp[m*C2_ + c] = v;
}

// -------------------------------------------------------------- launch -----
extern "C" void kernel_launch(void* const* d_in, const int* in_sizes, int n_in,
                              void* d_out, int out_size, void* d_ws, size_t ws_size,
                              hipStream_t stream) {
    const float* xyz    = (const float*)d_in[0];
    const float* points = (const float*)d_in[1];
    const float* W1     = (const float*)d_in[2];
    const float* b1     = (const float*)d_in[3];
    const float* g1     = (const float*)d_in[4];
    const float* be1    = (const float*)d_in[5];
    const float* W2     = (const float*)d_in[6];
    const float* b2     = (const float*)d_in[7];
    const float* g2     = (const float*)d_in[8];
    const float* be2    = (const float*)d_in[9];

    float* out_xyz = (float*)d_out;
    float* out_pts = (float*)d_out + B_*K_*3;

    (void)d_ws; (void)ws_size;

    transpose_w_kernel<<<64, 256, 0, stream>>>(W1, W2);   // + zeroes stats
    fps_kernel<<<B_, 1024, 0, stream>>>(xyz, out_xyz);
    knn_kernel<<<dim3(256, B_), 256, 0, stream>>>(xyz, out_xyz);
    stats1_kernel<<<NBLK, 256, 0, stream>>>(xyz, points, out_xyz, b1);
    gemm2_kernel<<<NBLK2, 256, 0, stream>>>(b2, g1, be1);
    final_kernel<<<B_*K_/2, 256, 0, stream>>>(g2, be2, out_pts);
}